// Round 4
// baseline (7869.785 us; speedup 1.0000x reference)
//
#include <hip/hip_runtime.h>
#include <stdint.h>

#define B_  256
#define T_  512
#define I_  256
#define H_  512
#define G3_ 1536

typedef _Float16 half8  __attribute__((ext_vector_type(8)));
typedef _Float16 half4v __attribute__((ext_vector_type(4)));
typedef float    float4v __attribute__((ext_vector_type(4)));
typedef unsigned long long u64;

__device__ __forceinline__ float sigmoid_f(float x) { return 1.f / (1.f + __expf(-x)); }
__device__ __forceinline__ float tanh_f(float x) {
  x = fminf(15.f, fmaxf(-15.f, x));
  float e = __expf(2.f * x);
  return (e - 1.f) / (e + 1.f);
}

union H16 { _Float16 h; unsigned short u; };

// ---------------------------------------------------------------------------
// Kernel A: igates[t][b][g] = (fp16) sum_k x[b][t][k] * w_ih[g][k] + bias[g]
// (unchanged — scan dominates)
// ---------------------------------------------------------------------------
__global__ __launch_bounds__(256) void igates_gemm(
    const float* __restrict__ x, const float* __restrict__ w_ih,
    const float* __restrict__ bias, _Float16* __restrict__ ig)
{
  __shared__ _Float16 Ash[64][72];
  __shared__ _Float16 Bsh[64][72];
  const int tid  = threadIdx.x;
  const int lane = tid & 63;
  const int wv   = tid >> 6;
  const int wm   = wv >> 1, wn = wv & 1;
  const int n0   = blockIdx.x * 64;
  const int m0   = blockIdx.y * 64;

  float4v acc[2][2];
  #pragma unroll
  for (int a = 0; a < 2; ++a)
    #pragma unroll
    for (int c = 0; c < 2; ++c) acc[a][c] = (float4v){0.f, 0.f, 0.f, 0.f};

  for (int kc = 0; kc < I_; kc += 64) {
    #pragma unroll
    for (int i = 0; i < 4; ++i) {
      int e   = tid + (i << 8);
      int row = e >> 4;
      int c4  = e & 15;
      int m   = m0 + row;
      int tt  = m >> 8, bb = m & 255;
      float4 va = *(const float4*)(x + ((size_t)bb * T_ + tt) * I_ + kc + (c4 << 2));
      *(half4v*)&Ash[row][c4 << 2] =
          (half4v){(_Float16)va.x, (_Float16)va.y, (_Float16)va.z, (_Float16)va.w};
      float4 vb = *(const float4*)(w_ih + (size_t)(n0 + row) * I_ + kc + (c4 << 2));
      *(half4v*)&Bsh[row][c4 << 2] =
          (half4v){(_Float16)vb.x, (_Float16)vb.y, (_Float16)vb.z, (_Float16)vb.w};
    }
    __syncthreads();
    #pragma unroll
    for (int ks = 0; ks < 2; ++ks) {
      int kk = (ks << 5) + ((lane >> 4) << 3);
      half8 a0 = *(const half8*)&Ash[(wm << 5) + (lane & 15)][kk];
      half8 a1 = *(const half8*)&Ash[(wm << 5) + 16 + (lane & 15)][kk];
      half8 b0 = *(const half8*)&Bsh[(wn << 5) + (lane & 15)][kk];
      half8 b1 = *(const half8*)&Bsh[(wn << 5) + 16 + (lane & 15)][kk];
      acc[0][0] = __builtin_amdgcn_mfma_f32_16x16x32_f16(a0, b0, acc[0][0], 0, 0, 0);
      acc[0][1] = __builtin_amdgcn_mfma_f32_16x16x32_f16(a0, b1, acc[0][1], 0, 0, 0);
      acc[1][0] = __builtin_amdgcn_mfma_f32_16x16x32_f16(a1, b0, acc[1][0], 0, 0, 0);
      acc[1][1] = __builtin_amdgcn_mfma_f32_16x16x32_f16(a1, b1, acc[1][1], 0, 0, 0);
    }
    __syncthreads();
  }
  #pragma unroll
  for (int mt = 0; mt < 2; ++mt)
    #pragma unroll
    for (int nt = 0; nt < 2; ++nt) {
      int mrow = m0 + (wm << 5) + (mt << 4) + ((lane >> 4) << 2);
      int ncol = n0 + (wn << 5) + (nt << 4) + (lane & 15);
      float bb = bias[ncol];
      #pragma unroll
      for (int r = 0; r < 4; ++r)
        ig[(size_t)(mrow + r) * G3_ + ncol] = (_Float16)(acc[mt][nt][r] + bb);
    }
}

// ---------------------------------------------------------------------------
// Kernel B: persistent GRU scan, v6 — dual-copy publish + sentinel-gated
// L2 (sc0) exchange. 128 WGs x 256 thr (v2's proven geometry).
//
// Producers publish each h(t+1) word TWICE, fire-and-forget, tagged
// ((fp16<<16)|(t+1)): (a) sc0 store -> stays in the local XCD L2 (fast copy);
// (b) relaxed agent-scope store -> coherent at the IF (guaranteed copy).
// No flags, no acks. Consumers gate on 8 sentinel words (32B/WG of spin
// traffic — v4's regression was 32KB/WG/round fabric congestion), then bulk
// load + validate every word (self-validating tags), re-loading stragglers.
// Fast path reads the sc0 copy (same-XCD L2 RT ~250-300cy, placement
// heuristic blk&7); on bounded timeout a wave falls back STICKILY to the
// agent-scope copy — always sound because that copy is always written.
// Parity double-buffer + single __syncthreads per step; overwrite safety as
// v4 (a tag-t+2 publish is data-dependent on completed tag-t reads of every
// thread in the group, through MFMA + the barrier).
// All waits bounded: worst case ~seconds then wrong answer — never a hang.
// ---------------------------------------------------------------------------
#define FAST_TO   8192
#define SLOW_TO   32768
#define STRAG_TO  4096

__global__ __launch_bounds__(256, 1) void gru_scan(
    const _Float16* __restrict__ ig, const float* __restrict__ w_hh,
    const float* __restrict__ b_n,
    uint32_t* __restrict__ hwf, uint32_t* __restrict__ hws)
{
  __shared__ _Float16 h_lds[2][16][520];   // double-buffered h(t)

  const int tid   = threadIdx.x;
  const int lane  = tid & 63;
  const int wv    = tid >> 6;
  const int blk   = blockIdx.x;
  const int gb    = ((blk & 7) << 1) | ((blk >> 3) & 1);  // 0..15
  const int gs    = blk >> 4;                              // 0..7 (slice)
  const int b0    = gb << 4;
  const int jw    = (gs << 6) + (wv << 4);
  const int cn    = lane & 15;
  const int rquad = lane >> 4;

  // ---- preload w_hh fragments ----
  half8 wfrag[3][16];
  #pragma unroll
  for (int g = 0; g < 3; ++g) {
    const float* wrow = w_hh + (size_t)(g * H_ + jw + cn) * H_;
    #pragma unroll
    for (int ks = 0; ks < 16; ++ks) {
      int k = (ks << 5) + (rquad << 3);
      half8 w;
      #pragma unroll
      for (int i = 0; i < 8; ++i) w[i] = (_Float16)wrow[k + i];
      wfrag[g][ks] = w;
    }
  }
  const float bnv = b_n[jw + cn];

  int mode = 0;   // 0 = fast (sc0/L2 copy), 1 = slow (agent copy); sticky

  for (int t = 0; t < T_; ++t) {
    const int p = t & 1;
    const unsigned tag = (unsigned)t;
    const uint32_t* fbase = hwf + (size_t)p * (B_ * H_);
    const uint32_t* sbase = hws + (size_t)p * (B_ * H_);

    // (A) ig prefetch — overlaps the sentinel wait
    float igv[3][4];
    {
      const _Float16* igb =
          ig + (size_t)(t * B_ + b0 + (rquad << 2)) * G3_ + jw + cn;
      #pragma unroll
      for (int g = 0; g < 3; ++g)
        #pragma unroll
        for (int r = 0; r < 4; ++r)
          igv[g][r] = (float)igb[(size_t)r * G3_ + g * H_];
    }

    // (B) sentinel detector: lanes 0..7 poll one word per slice
    //     (row b0+15, col s*64+63) — 32B per WG per round.
    {
      const uint32_t* fsent = fbase + (((size_t)(b0 + 15)) << 9) + (lane << 6) + 63;
      const uint32_t* ssent = sbase + (((size_t)(b0 + 15)) << 9) + (lane << 6) + 63;
      int rounds = 0;
      bool done = false;
      while (!done) {
        bool fresh = true;
        if (lane < 8) {
          unsigned v;
          if (mode == 0) {
            asm volatile("global_load_dword %0, %1, off sc0\n\t"
                         "s_waitcnt vmcnt(0)"
                         : "=v"(v) : "v"(fsent) : "memory");
          } else {
            v = __hip_atomic_load(ssent, __ATOMIC_RELAXED,
                                  __HIP_MEMORY_SCOPE_AGENT);
          }
          fresh = ((v & 0xffffu) == tag);
        }
        done = __all(fresh);
        if (!done) {
          ++rounds;
          if (mode == 0) {
            if (rounds > FAST_TO) { mode = 1; rounds = 0; }   // sticky fallback
          } else {
            if (rounds > SLOW_TO) break;                      // give up (bounded)
          }
        }
      }
    }

    // (C) bulk load 16 u64/thread + validate tags; straggler retries bounded
    u64 w64[16];
    {
      const char* A0 = (mode == 0)
          ? (const char*)fbase + (size_t)b0 * 2048 + (size_t)tid * 8
          : (const char*)sbase + (size_t)b0 * 2048 + (size_t)tid * 8;
      bool ok = false;
      for (int r2 = 0; !ok && r2 < STRAG_TO; ++r2) {
        if (mode == 0) {
          asm volatile(
            "global_load_dwordx2 %[o0],  %[a0], off sc0\n\t"
            "global_load_dwordx2 %[o1],  %[a0], off offset:2048 sc0\n\t"
            "global_load_dwordx2 %[o2],  %[a1], off sc0\n\t"
            "global_load_dwordx2 %[o3],  %[a1], off offset:2048 sc0\n\t"
            "global_load_dwordx2 %[o4],  %[a2], off sc0\n\t"
            "global_load_dwordx2 %[o5],  %[a2], off offset:2048 sc0\n\t"
            "global_load_dwordx2 %[o6],  %[a3], off sc0\n\t"
            "global_load_dwordx2 %[o7],  %[a3], off offset:2048 sc0\n\t"
            "global_load_dwordx2 %[o8],  %[a4], off sc0\n\t"
            "global_load_dwordx2 %[o9],  %[a4], off offset:2048 sc0\n\t"
            "global_load_dwordx2 %[o10], %[a5], off sc0\n\t"
            "global_load_dwordx2 %[o11], %[a5], off offset:2048 sc0\n\t"
            "global_load_dwordx2 %[o12], %[a6], off sc0\n\t"
            "global_load_dwordx2 %[o13], %[a6], off offset:2048 sc0\n\t"
            "global_load_dwordx2 %[o14], %[a7], off sc0\n\t"
            "global_load_dwordx2 %[o15], %[a7], off offset:2048 sc0\n\t"
            "s_waitcnt vmcnt(0)"
            : [o0] "=v"(w64[0]),  [o1] "=v"(w64[1]),  [o2] "=v"(w64[2]),
              [o3] "=v"(w64[3]),  [o4] "=v"(w64[4]),  [o5] "=v"(w64[5]),
              [o6] "=v"(w64[6]),  [o7] "=v"(w64[7]),  [o8] "=v"(w64[8]),
              [o9] "=v"(w64[9]),  [o10]"=v"(w64[10]), [o11]"=v"(w64[11]),
              [o12]"=v"(w64[12]), [o13]"=v"(w64[13]), [o14]"=v"(w64[14]),
              [o15]"=v"(w64[15])
            : [a0]"v"(A0),          [a1]"v"(A0 + 4096),  [a2]"v"(A0 + 8192),
              [a3]"v"(A0 + 12288),  [a4]"v"(A0 + 16384), [a5]"v"(A0 + 20480),
              [a6]"v"(A0 + 24576),  [a7]"v"(A0 + 28672)
            : "memory");
        } else {
          #pragma unroll
          for (int i = 0; i < 16; ++i)
            w64[i] = __hip_atomic_load((const u64*)(A0 + (size_t)i * 2048),
                                       __ATOMIC_RELAXED, __HIP_MEMORY_SCOPE_AGENT);
        }
        ok = true;
        #pragma unroll
        for (int i = 0; i < 16; ++i) {
          unsigned lo = (unsigned)w64[i] & 0xffffu;
          unsigned hi = (unsigned)(w64[i] >> 32) & 0xffffu;
          ok = ok && (lo == tag) && (hi == tag);
        }
      }
    }

    // (D) stage into LDS buffer p (strip tags, pack 2 fp16 per u32 write)
    #pragma unroll
    for (int i = 0; i < 16; ++i) {
      unsigned packed = ((unsigned)(w64[i] >> 16) & 0xffffu) |
                        ((unsigned)(w64[i] >> 48) << 16);
      *(unsigned*)&h_lds[p][i][tid << 1] = packed;
    }

    // (E) the ONLY barrier per step
    __syncthreads();

    // (F) MFMA: 3 gates x full K=512 per wave
    float4v acc[3];
    acc[0] = (float4v){0.f, 0.f, 0.f, 0.f};
    acc[1] = acc[0];
    acc[2] = acc[0];
    #pragma unroll
    for (int ks = 0; ks < 16; ++ks) {
      half8 a = *(const half8*)&h_lds[p][cn][(ks << 5) + (rquad << 3)];
      acc[0] = __builtin_amdgcn_mfma_f32_16x16x32_f16(a, wfrag[0][ks], acc[0], 0, 0, 0);
      acc[1] = __builtin_amdgcn_mfma_f32_16x16x32_f16(a, wfrag[1][ks], acc[1], 0, 0, 0);
      acc[2] = __builtin_amdgcn_mfma_f32_16x16x32_f16(a, wfrag[2][ks], acc[2], 0, 0, 0);
    }

    // (G) epilogue + dual fire-and-forget tagged publish of h(t+1)
    const size_t pn = (size_t)((t + 1) & 1) * (B_ * H_);
    const unsigned tagw = (unsigned)(t + 1);
    #pragma unroll
    for (int r = 0; r < 4; ++r) {
      float rg = sigmoid_f(igv[0][r] + acc[0][r]);
      float zg = sigmoid_f(igv[1][r] + acc[1][r]);
      float nv = tanh_f(igv[2][r] + rg * (acc[2][r] + bnv));
      float hp = (float)h_lds[p][(rquad << 2) + r][jw + cn];
      H16 hv; hv.h = (_Float16)(nv + zg * (hp - nv));
      uint32_t val = ((unsigned)hv.u << 16) | tagw;
      size_t off = (((size_t)(b0 + (rquad << 2) + r)) << 9) + jw + cn;
      uint32_t* fdst = hwf + pn + off;
      asm volatile("global_store_dword %0, %1, off sc0"
                   :: "v"(fdst), "v"(val) : "memory");
      __hip_atomic_store(hws + pn + off, val,
                         __ATOMIC_RELAXED, __HIP_MEMORY_SCOPE_AGENT);
    }
  }
}

// ---------------------------------------------------------------------------
// Kernel C: e[b] = h_T[b] . w_proj + b_proj   (agent copy, parity 0; all
// dirty lines written back by the dispatch-boundary release)
// ---------------------------------------------------------------------------
__global__ __launch_bounds__(64) void proj_kernel(
    const uint32_t* __restrict__ h, const float* __restrict__ w_proj,
    const float* __restrict__ b_proj, float* __restrict__ out)
{
  int b = blockIdx.x;
  int lane = threadIdx.x;
  float s = 0.f;
  #pragma unroll
  for (int i = 0; i < 8; ++i) {
    int j = lane + (i << 6);
    H16 v; v.u = (unsigned short)(h[((size_t)b << 9) + j] >> 16);
    s += (float)v.h * w_proj[j];
  }
  #pragma unroll
  for (int off = 32; off > 0; off >>= 1) s += __shfl_down(s, off, 64);
  if (lane == 0) out[b] = s + b_proj[0];
}

// ---------------------------------------------------------------------------
extern "C" void kernel_launch(void* const* d_in, const int* in_sizes, int n_in,
                              void* d_out, int out_size, void* d_ws, size_t ws_size,
                              hipStream_t stream) {
  const float* x      = (const float*)d_in[0];
  const float* w_ih   = (const float*)d_in[1];
  const float* w_hh   = (const float*)d_in[2];
  const float* bias   = (const float*)d_in[3];
  const float* b_n    = (const float*)d_in[4];
  const float* w_proj = (const float*)d_in[5];
  const float* b_proj = (const float*)d_in[6];
  float* out = (float*)d_out;

  char* ws = (char*)d_ws;
  const size_t IG_BYTES = (size_t)T_ * B_ * G3_ * sizeof(_Float16); // 402,653,184
  const size_t HB_U32   = (size_t)B_ * H_;                          // per parity
  _Float16* igbuf = (_Float16*)ws;
  uint32_t* hwf   = (uint32_t*)(ws + IG_BYTES);                    // fast copy (2 parities)
  uint32_t* hws   = hwf + 2 * HB_U32;                              // agent copy (2 parities)

  // zero all tagged-h buffers (tag 0 == h(0) == 0) — capture-safe
  hipMemsetAsync(hwf, 0, 4 * HB_U32 * sizeof(uint32_t), stream);

  dim3 gridA(G3_ / 64, (T_ * B_) / 64);   // (24, 2048)
  igates_gemm<<<gridA, 256, 0, stream>>>(x, w_ih, bias, igbuf);
  gru_scan<<<128, 256, 0, stream>>>(igbuf, w_hh, b_n, hwf, hws);
  proj_kernel<<<B_, 64, 0, stream>>>(hws, w_proj, b_proj, out);
}

// Round 5
// 2792.603 us; speedup vs baseline: 2.8181x; 2.8181x over previous
//
#include <hip/hip_runtime.h>
#include <stdint.h>

#define B_  256
#define T_  512
#define I_  256
#define H_  512
#define G3_ 1536

typedef _Float16 half8  __attribute__((ext_vector_type(8)));
typedef _Float16 half4v __attribute__((ext_vector_type(4)));
typedef float    float4v __attribute__((ext_vector_type(4)));
typedef unsigned long long u64;

__device__ __forceinline__ float sigmoid_f(float x) { return 1.f / (1.f + __expf(-x)); }
__device__ __forceinline__ float tanh_f(float x) {
  x = fminf(15.f, fmaxf(-15.f, x));
  float e = __expf(2.f * x);
  return (e - 1.f) / (e + 1.f);
}

union H16 { _Float16 h; unsigned short u; };

// ---------------------------------------------------------------------------
// Kernel A: igates[t][b][g] = (fp16) sum_k x[b][t][k] * w_ih[g][k] + bias[g]
// (unchanged — scan dominates)
// ---------------------------------------------------------------------------
__global__ __launch_bounds__(256) void igates_gemm(
    const float* __restrict__ x, const float* __restrict__ w_ih,
    const float* __restrict__ bias, _Float16* __restrict__ ig)
{
  __shared__ _Float16 Ash[64][72];
  __shared__ _Float16 Bsh[64][72];
  const int tid  = threadIdx.x;
  const int lane = tid & 63;
  const int wv   = tid >> 6;
  const int wm   = wv >> 1, wn = wv & 1;
  const int n0   = blockIdx.x * 64;
  const int m0   = blockIdx.y * 64;

  float4v acc[2][2];
  #pragma unroll
  for (int a = 0; a < 2; ++a)
    #pragma unroll
    for (int c = 0; c < 2; ++c) acc[a][c] = (float4v){0.f, 0.f, 0.f, 0.f};

  for (int kc = 0; kc < I_; kc += 64) {
    #pragma unroll
    for (int i = 0; i < 4; ++i) {
      int e   = tid + (i << 8);
      int row = e >> 4;
      int c4  = e & 15;
      int m   = m0 + row;
      int tt  = m >> 8, bb = m & 255;
      float4 va = *(const float4*)(x + ((size_t)bb * T_ + tt) * I_ + kc + (c4 << 2));
      *(half4v*)&Ash[row][c4 << 2] =
          (half4v){(_Float16)va.x, (_Float16)va.y, (_Float16)va.z, (_Float16)va.w};
      float4 vb = *(const float4*)(w_ih + (size_t)(n0 + row) * I_ + kc + (c4 << 2));
      *(half4v*)&Bsh[row][c4 << 2] =
          (half4v){(_Float16)vb.x, (_Float16)vb.y, (_Float16)vb.z, (_Float16)vb.w};
    }
    __syncthreads();
    #pragma unroll
    for (int ks = 0; ks < 2; ++ks) {
      int kk = (ks << 5) + ((lane >> 4) << 3);
      half8 a0 = *(const half8*)&Ash[(wm << 5) + (lane & 15)][kk];
      half8 a1 = *(const half8*)&Ash[(wm << 5) + 16 + (lane & 15)][kk];
      half8 b0 = *(const half8*)&Bsh[(wn << 5) + (lane & 15)][kk];
      half8 b1 = *(const half8*)&Bsh[(wn << 5) + 16 + (lane & 15)][kk];
      acc[0][0] = __builtin_amdgcn_mfma_f32_16x16x32_f16(a0, b0, acc[0][0], 0, 0, 0);
      acc[0][1] = __builtin_amdgcn_mfma_f32_16x16x32_f16(a0, b1, acc[0][1], 0, 0, 0);
      acc[1][0] = __builtin_amdgcn_mfma_f32_16x16x32_f16(a1, b0, acc[1][0], 0, 0, 0);
      acc[1][1] = __builtin_amdgcn_mfma_f32_16x16x32_f16(a1, b1, acc[1][1], 0, 0, 0);
    }
    __syncthreads();
  }
  #pragma unroll
  for (int mt = 0; mt < 2; ++mt)
    #pragma unroll
    for (int nt = 0; nt < 2; ++nt) {
      int mrow = m0 + (wm << 5) + (mt << 4) + ((lane >> 4) << 2);
      int ncol = n0 + (wn << 5) + (nt << 4) + (lane & 15);
      float bb = bias[ncol];
      #pragma unroll
      for (int r = 0; r < 4; ++r)
        ig[(size_t)(mrow + r) * G3_ + ncol] = (_Float16)(acc[mt][nt][r] + bb);
    }
}

// ---------------------------------------------------------------------------
// Kernel B: persistent GRU scan, v7 — all agent-scope (the only exchange
// measured to work: v2=3.0us/step, v4=3.5us/step; v6's sc0/L2 path is broken
// on HW). Combines v4's tagged words (no producer ack RT) with v2's
// tiny-footprint spin (sentinels, not full re-poll — v4's congestion killer).
//
// Per step: fire-and-forget tagged publish ((fp16<<16)|t+1, 4 u32 agent
// stores/thread) -> sentinel spin (128 words = 512B/WG/round, covering every
// row x slice x producer-wave) -> ONE 32KB bulk tagged load + pending-only
// straggler retries -> LDS stage -> single barrier -> MFMA -> epilogue.
//
// wfrag pinned in VGPRs via asm "+v" (v2/v4 VGPR_Count 136-164 < 192 proves
// the compiler re-built weights from L2 every step: ~500cy/step of loads+cvt
// on the critical path). Budget: ~280 VGPR at launch_bounds(256,1) -> 512
// budget, still 1 wave/SIMD.
//
// Overwrite safety (parity double-buffer, proven on HW by v4): a tag-t+2
// publish at location L is transitively data-dependent on every consumer
// thread's completed tag-t read of L, through that consumer WG's barrier and
// its own t+1 publish. All spins bounded -> never a hung container.
// ---------------------------------------------------------------------------
__global__ __launch_bounds__(256, 1) void gru_scan(
    const _Float16* __restrict__ ig, const float* __restrict__ w_hh,
    const float* __restrict__ b_n, uint32_t* __restrict__ hw)
{
  __shared__ _Float16 h_lds[2][16][520];   // double-buffered h(t)

  const int tid   = threadIdx.x;
  const int lane  = tid & 63;
  const int wv    = tid >> 6;
  const int blk   = blockIdx.x;
  const int gb    = ((blk & 7) << 1) | ((blk >> 3) & 1);  // 0..15 b-group
  const int gs    = blk >> 4;                              // 0..7 col-slice
  const int b0    = gb << 4;
  const int jw    = (gs << 6) + (wv << 4);
  const int cn    = lane & 15;
  const int rquad = lane >> 4;

  // ---- preload w_hh fragments, then PIN them in VGPRs ----
  half8 wfrag[3][16];
  #pragma unroll
  for (int g = 0; g < 3; ++g) {
    const float* wrow = w_hh + (size_t)(g * H_ + jw + cn) * H_;
    #pragma unroll
    for (int ks = 0; ks < 16; ++ks) {
      int k = (ks << 5) + (rquad << 3);
      half8 w;
      #pragma unroll
      for (int i = 0; i < 8; ++i) w[i] = (_Float16)wrow[k + i];
      wfrag[g][ks] = w;
    }
  }
  #pragma unroll
  for (int g = 0; g < 3; ++g)
    #pragma unroll
    for (int ks = 0; ks < 16; ++ks)
      asm volatile("" : "+v"(wfrag[g][ks]));   // opaque: cannot rematerialize
  const float bnv = b_n[jw + cn];

  // sentinel set: lane polls 2 words -> 128 words/WG covering all 16 rows x
  // 8 slices; col offset (srow*4+3) spreads across all 4 producer waves.
  const int srow  = lane & 15;
  const int ssl   = lane >> 4;
  const int scol0 = (ssl << 6)       + ((srow << 2) | 3);
  const int scol1 = ((ssl + 4) << 6) + ((srow << 2) | 3);

  for (int t = 0; t < T_; ++t) {
    const int p = t & 1;
    const unsigned tag = (unsigned)t;
    const uint32_t* base = hw + (size_t)p * (B_ * H_);

    // (A) ig prefetch — overlaps the sentinel wait
    float igv[3][4];
    {
      const _Float16* igb =
          ig + (size_t)(t * B_ + b0 + (rquad << 2)) * G3_ + jw + cn;
      #pragma unroll
      for (int g = 0; g < 3; ++g)
        #pragma unroll
        for (int r = 0; r < 4; ++r)
          igv[g][r] = (float)igb[(size_t)r * G3_ + g * H_];
    }

    // (B) sentinel spin: 512B/WG/round, agent-scope, bounded
    {
      const uint32_t* s0 = base + (((size_t)(b0 + srow)) << 9) + scol0;
      const uint32_t* s1 = base + (((size_t)(b0 + srow)) << 9) + scol1;
      bool done = false;
      for (int rnd = 0; !done && rnd < (1 << 20); ++rnd) {
        unsigned a = __hip_atomic_load(s0, __ATOMIC_RELAXED,
                                       __HIP_MEMORY_SCOPE_AGENT);
        unsigned b = __hip_atomic_load(s1, __ATOMIC_RELAXED,
                                       __HIP_MEMORY_SCOPE_AGENT);
        done = __all(((a & 0xffffu) == tag) && ((b & 0xffffu) == tag));
      }
    }

    // (C) ONE bulk load (16 u64/thread = 32KB/WG) + pending-only retries
    u64 w64[16];
    {
      const u64* A0 = (const u64*)((const char*)base + (size_t)b0 * 2048) + tid;
      unsigned pend = 0xffffu;
      for (int r2 = 0; __any(pend != 0u) && r2 < (1 << 14); ++r2) {
        #pragma unroll
        for (int i = 0; i < 16; ++i)
          if (pend & (1u << i))
            w64[i] = __hip_atomic_load(A0 + ((size_t)i << 8),
                                       __ATOMIC_RELAXED, __HIP_MEMORY_SCOPE_AGENT);
        unsigned np = 0u;
        #pragma unroll
        for (int i = 0; i < 16; ++i)
          if (pend & (1u << i)) {
            unsigned lo = (unsigned)w64[i] & 0xffffu;
            unsigned hi = (unsigned)(w64[i] >> 32) & 0xffffu;
            if ((lo != tag) || (hi != tag)) np |= (1u << i);
          }
        pend = np;
      }
    }

    // (D) stage into LDS buffer p (strip tags, 2 fp16 per u32 write)
    #pragma unroll
    for (int i = 0; i < 16; ++i) {
      unsigned packed = ((unsigned)(w64[i] >> 16) & 0xffffu) |
                        ((unsigned)(w64[i] >> 48) << 16);
      *(unsigned*)&h_lds[p][i][tid << 1] = packed;
    }

    // (E) the ONLY barrier per step
    __syncthreads();

    // (F) MFMA: 3 gates x full K=512 per wave
    float4v acc[3];
    acc[0] = (float4v){0.f, 0.f, 0.f, 0.f};
    acc[1] = acc[0];
    acc[2] = acc[0];
    #pragma unroll
    for (int ks = 0; ks < 16; ++ks) {
      half8 a = *(const half8*)&h_lds[p][cn][(ks << 5) + (rquad << 3)];
      acc[0] = __builtin_amdgcn_mfma_f32_16x16x32_f16(a, wfrag[0][ks], acc[0], 0, 0, 0);
      acc[1] = __builtin_amdgcn_mfma_f32_16x16x32_f16(a, wfrag[1][ks], acc[1], 0, 0, 0);
      acc[2] = __builtin_amdgcn_mfma_f32_16x16x32_f16(a, wfrag[2][ks], acc[2], 0, 0, 0);
    }

    // (G) epilogue + fire-and-forget tagged publish of h(t+1)
    const size_t pn = (size_t)((t + 1) & 1) * (B_ * H_);
    const unsigned tagw = (unsigned)(t + 1);
    #pragma unroll
    for (int r = 0; r < 4; ++r) {
      float rg = sigmoid_f(igv[0][r] + acc[0][r]);
      float zg = sigmoid_f(igv[1][r] + acc[1][r]);
      float nv = tanh_f(igv[2][r] + rg * (acc[2][r] + bnv));
      float hp = (float)h_lds[p][(rquad << 2) + r][jw + cn];
      H16 hv; hv.h = (_Float16)(nv + zg * (hp - nv));
      __hip_atomic_store(
          hw + pn + (((size_t)(b0 + (rquad << 2) + r)) << 9) + jw + cn,
          ((unsigned)hv.u << 16) | tagw,
          __ATOMIC_RELAXED, __HIP_MEMORY_SCOPE_AGENT);
    }
  }
}

// ---------------------------------------------------------------------------
// Kernel C: e[b] = h_T[b] . w_proj + b_proj   (tagged-u32, parity 0; visible
// via the dispatch-boundary release)
// ---------------------------------------------------------------------------
__global__ __launch_bounds__(64) void proj_kernel(
    const uint32_t* __restrict__ h, const float* __restrict__ w_proj,
    const float* __restrict__ b_proj, float* __restrict__ out)
{
  int b = blockIdx.x;
  int lane = threadIdx.x;
  float s = 0.f;
  #pragma unroll
  for (int i = 0; i < 8; ++i) {
    int j = lane + (i << 6);
    H16 v; v.u = (unsigned short)(h[((size_t)b << 9) + j] >> 16);
    s += (float)v.h * w_proj[j];
  }
  #pragma unroll
  for (int off = 32; off > 0; off >>= 1) s += __shfl_down(s, off, 64);
  if (lane == 0) out[b] = s + b_proj[0];
}

// ---------------------------------------------------------------------------
extern "C" void kernel_launch(void* const* d_in, const int* in_sizes, int n_in,
                              void* d_out, int out_size, void* d_ws, size_t ws_size,
                              hipStream_t stream) {
  const float* x      = (const float*)d_in[0];
  const float* w_ih   = (const float*)d_in[1];
  const float* w_hh   = (const float*)d_in[2];
  const float* bias   = (const float*)d_in[3];
  const float* b_n    = (const float*)d_in[4];
  const float* w_proj = (const float*)d_in[5];
  const float* b_proj = (const float*)d_in[6];
  float* out = (float*)d_out;

  char* ws = (char*)d_ws;
  const size_t IG_BYTES = (size_t)T_ * B_ * G3_ * sizeof(_Float16); // 402,653,184
  const size_t HB_U32   = (size_t)B_ * H_;                          // per parity
  _Float16* igbuf = (_Float16*)ws;
  uint32_t* hw    = (uint32_t*)(ws + IG_BYTES);                     // 2 parities

  // zero tagged-h parity buffers (tag 0 == h(0) == 0) — capture-safe
  hipMemsetAsync(hw, 0, 2 * HB_U32 * sizeof(uint32_t), stream);

  dim3 gridA(G3_ / 64, (T_ * B_) / 64);   // (24, 2048)
  igates_gemm<<<gridA, 256, 0, stream>>>(x, w_ih, bias, igbuf);
  gru_scan<<<128, 256, 0, stream>>>(igbuf, w_hh, b_n, hw);
  proj_kernel<<<B_, 64, 0, stream>>>(hw, w_proj, b_proj, out);
}

// Round 6
// 2199.420 us; speedup vs baseline: 3.5781x; 1.2697x over previous
//
#include <hip/hip_runtime.h>
#include <stdint.h>

#define B_  256
#define T_  512
#define I_  256
#define H_  512
#define G3_ 1536

typedef _Float16 half8  __attribute__((ext_vector_type(8)));
typedef _Float16 half4v __attribute__((ext_vector_type(4)));
typedef float    float4v __attribute__((ext_vector_type(4)));
typedef unsigned long long u64;

__device__ __forceinline__ float sigmoid_f(float x) { return 1.f / (1.f + __expf(-x)); }
__device__ __forceinline__ float tanh_f(float x) {
  x = fminf(15.f, fmaxf(-15.f, x));
  float e = __expf(2.f * x);
  return (e - 1.f) / (e + 1.f);
}

union H16 { _Float16 h; unsigned short u; };

// ---------------------------------------------------------------------------
// Kernel A: igates[t][b][g] = (fp16) sum_k x[b][t][k] * w_ih[g][k] + bias[g]
// (unchanged — scan dominates)
// ---------------------------------------------------------------------------
__global__ __launch_bounds__(256) void igates_gemm(
    const float* __restrict__ x, const float* __restrict__ w_ih,
    const float* __restrict__ bias, _Float16* __restrict__ ig)
{
  __shared__ _Float16 Ash[64][72];
  __shared__ _Float16 Bsh[64][72];
  const int tid  = threadIdx.x;
  const int lane = tid & 63;
  const int wv   = tid >> 6;
  const int wm   = wv >> 1, wn = wv & 1;
  const int n0   = blockIdx.x * 64;
  const int m0   = blockIdx.y * 64;

  float4v acc[2][2];
  #pragma unroll
  for (int a = 0; a < 2; ++a)
    #pragma unroll
    for (int c = 0; c < 2; ++c) acc[a][c] = (float4v){0.f, 0.f, 0.f, 0.f};

  for (int kc = 0; kc < I_; kc += 64) {
    #pragma unroll
    for (int i = 0; i < 4; ++i) {
      int e   = tid + (i << 8);
      int row = e >> 4;
      int c4  = e & 15;
      int m   = m0 + row;
      int tt  = m >> 8, bb = m & 255;
      float4 va = *(const float4*)(x + ((size_t)bb * T_ + tt) * I_ + kc + (c4 << 2));
      *(half4v*)&Ash[row][c4 << 2] =
          (half4v){(_Float16)va.x, (_Float16)va.y, (_Float16)va.z, (_Float16)va.w};
      float4 vb = *(const float4*)(w_ih + (size_t)(n0 + row) * I_ + kc + (c4 << 2));
      *(half4v*)&Bsh[row][c4 << 2] =
          (half4v){(_Float16)vb.x, (_Float16)vb.y, (_Float16)vb.z, (_Float16)vb.w};
    }
    __syncthreads();
    #pragma unroll
    for (int ks = 0; ks < 2; ++ks) {
      int kk = (ks << 5) + ((lane >> 4) << 3);
      half8 a0 = *(const half8*)&Ash[(wm << 5) + (lane & 15)][kk];
      half8 a1 = *(const half8*)&Ash[(wm << 5) + 16 + (lane & 15)][kk];
      half8 b0 = *(const half8*)&Bsh[(wn << 5) + (lane & 15)][kk];
      half8 b1 = *(const half8*)&Bsh[(wn << 5) + 16 + (lane & 15)][kk];
      acc[0][0] = __builtin_amdgcn_mfma_f32_16x16x32_f16(a0, b0, acc[0][0], 0, 0, 0);
      acc[0][1] = __builtin_amdgcn_mfma_f32_16x16x32_f16(a0, b1, acc[0][1], 0, 0, 0);
      acc[1][0] = __builtin_amdgcn_mfma_f32_16x16x32_f16(a1, b0, acc[1][0], 0, 0, 0);
      acc[1][1] = __builtin_amdgcn_mfma_f32_16x16x32_f16(a1, b1, acc[1][1], 0, 0, 0);
    }
    __syncthreads();
  }
  #pragma unroll
  for (int mt = 0; mt < 2; ++mt)
    #pragma unroll
    for (int nt = 0; nt < 2; ++nt) {
      int mrow = m0 + (wm << 5) + (mt << 4) + ((lane >> 4) << 2);
      int ncol = n0 + (wn << 5) + (nt << 4) + (lane & 15);
      float bb = bias[ncol];
      #pragma unroll
      for (int r = 0; r < 4; ++r)
        ig[(size_t)(mrow + r) * G3_ + ncol] = (_Float16)(acc[mt][nt][r] + bb);
    }
}

// ---------------------------------------------------------------------------
// Kernel B: persistent GRU scan, v8 — v2's measured-best flag protocol
// (drain -> flag -> load: zero stale words, zero retries), with every
// overhead around it removed:
//   * per-WAVE flags (32/group): s_waitcnt drains the wave's own stores, so
//     the flag needs NO pre-barrier (v2 had one).
//   * direct fp16 2B publish: a wave's tile is 16 cols wide, so direct u16
//     stores coalesce identically (32B segments) to v2's repacked u64 —
//     the LDS repack + its barrier were pure overhead.
//   * parity-double-buffered LDS h => ONE __syncthreads per step (v2: 4).
//   * no s_sleep in the spin (64cy wake jitter); sticky per-lane polling.
//
// Safety (same inductive proof as v2, per-wave granularity): wave W's flag
// == t+1 implies W's h(t+1) publish drained, which implies W's MFMA and its
// bulk-load of h(t) retired (data dependence through the stage barrier).
// A producer needs ALL 32 wave-flags >= t+1 before touching parity (t+2)&1,
// so no word still needed by any consumer is ever overwritten. Flags are
// monotonic; poll uses >=. All spins bounded -> never a hung container.
// ---------------------------------------------------------------------------
__global__ __launch_bounds__(256, 1) void gru_scan(
    const _Float16* __restrict__ ig, const float* __restrict__ w_hh,
    const float* __restrict__ b_n,
    _Float16* __restrict__ hb0, _Float16* __restrict__ hb1, int* flags)
{
  __shared__ _Float16 h_lds[2][16][520];   // parity-double-buffered h(t)

  const int tid   = threadIdx.x;
  const int lane  = tid & 63;
  const int wv    = tid >> 6;                 // wave 0..3
  const int blk   = blockIdx.x;
  // XCD co-location heuristic (all 8 slices of a b-group share blk&7)
  const int gb    = ((blk & 7) << 1) | ((blk >> 3) & 1);  // 0..15 b-group
  const int gs    = blk >> 4;                              // 0..7 col-slice
  const int b0    = gb << 4;
  const int jw    = (gs << 6) + (wv << 4);    // first global h-col of this wave
  const int cn    = lane & 15;
  const int rquad = lane >> 4;

  // ---- preload w_hh fragments (as v2; no pin — pin measured ineffective) ----
  half8 wfrag[3][16];
  #pragma unroll
  for (int g = 0; g < 3; ++g) {
    const float* wrow = w_hh + (size_t)(g * H_ + jw + cn) * H_;
    #pragma unroll
    for (int ks = 0; ks < 16; ++ks) {
      int k = (ks << 5) + (rquad << 3);
      half8 w;
      #pragma unroll
      for (int i = 0; i < 8; ++i) w[i] = (_Float16)wrow[k + i];
      wfrag[g][ks] = w;
    }
  }
  const float bnv = b_n[jw + cn];

  _Float16* bufs[2] = { hb0, hb1 };
  int* fbase = flags + (gb << 5);             // this group's 32 wave-flags

  for (int t = 0; t < T_; ++t) {
    const int p = t & 1;

    // (A) ig prefetch — independent of peers, overlaps the flag spin
    float igv[3][4];
    {
      const _Float16* igb =
          ig + (size_t)(t * B_ + b0 + (rquad << 2)) * G3_ + jw + cn;
      #pragma unroll
      for (int g = 0; g < 3; ++g)
        #pragma unroll
        for (int r = 0; r < 4; ++r)
          igv[g][r] = (float)igb[(size_t)r * G3_ + g * H_];
    }

    // (B) flag spin: 32 wave-flags, lanes 0..31 one each, sticky per-lane,
    //     no sleep. Bounded (hang-safety valve).
    if (t > 0) {
      bool done_lane = (lane >= 32);
      const int* fp = fbase + lane;
      bool done = false;
      for (int rnd = 0; !done && rnd < (1 << 20); ++rnd) {
        if (!done_lane) {
          int v = __hip_atomic_load(fp, __ATOMIC_RELAXED,
                                    __HIP_MEMORY_SCOPE_AGENT);
          done_lane = (v >= t);
        }
        done = __all(done_lane);
      }
    }

    // (C) bulk load h(t): 16 rows x 512 fp16 = 2048 u64, 8 per thread,
    //     coalesced, one shot (flags guarantee freshness — no retries)
    u64 hv8[8];
    {
      const _Float16* hsrc = bufs[p] + ((size_t)b0 << 9);
      #pragma unroll
      for (int i = 0; i < 8; ++i) {
        int idx = (i << 8) + tid;
        int row = idx >> 7, c = idx & 127;
        hv8[i] = __hip_atomic_load(
            (const u64*)(hsrc + ((size_t)row << 9)) + c,
            __ATOMIC_RELAXED, __HIP_MEMORY_SCOPE_AGENT);
      }
    }

    // (D) stage into LDS parity buffer p
    #pragma unroll
    for (int i = 0; i < 8; ++i) {
      int idx = (i << 8) + tid;
      *(u64*)&h_lds[p][idx >> 7][(idx & 127) << 2] = hv8[i];
    }

    // (E) the ONLY barrier per step
    __syncthreads();

    // (F) MFMA: 3 gates x full K=512 per wave
    float4v acc[3];
    acc[0] = (float4v){0.f, 0.f, 0.f, 0.f};
    acc[1] = acc[0];
    acc[2] = acc[0];
    #pragma unroll
    for (int ks = 0; ks < 16; ++ks) {
      half8 a = *(const half8*)&h_lds[p][cn][(ks << 5) + (rquad << 3)];
      acc[0] = __builtin_amdgcn_mfma_f32_16x16x32_f16(a, wfrag[0][ks], acc[0], 0, 0, 0);
      acc[1] = __builtin_amdgcn_mfma_f32_16x16x32_f16(a, wfrag[1][ks], acc[1], 0, 0, 0);
      acc[2] = __builtin_amdgcn_mfma_f32_16x16x32_f16(a, wfrag[2][ks], acc[2], 0, 0, 0);
    }

    // (G) epilogue -> direct fp16 publish -> per-wave drain -> wave flag
    {
      unsigned short* hnext = (unsigned short*)bufs[(t + 1) & 1];
      #pragma unroll
      for (int r = 0; r < 4; ++r) {
        float rg = sigmoid_f(igv[0][r] + acc[0][r]);
        float zg = sigmoid_f(igv[1][r] + acc[1][r]);
        float nv = tanh_f(igv[2][r] + rg * (acc[2][r] + bnv));
        float hp = (float)h_lds[p][(rquad << 2) + r][jw + cn];
        H16 hv; hv.h = (_Float16)(nv + zg * (hp - nv));
        __hip_atomic_store(
            hnext + (((size_t)(b0 + (rquad << 2) + r)) << 9) + jw + cn,
            hv.u, __ATOMIC_RELAXED, __HIP_MEMORY_SCOPE_AGENT);
      }
      __builtin_amdgcn_s_waitcnt(0);   // wave's stores acked at coherence point
      if (lane == 0)
        __hip_atomic_store(fbase + (gs << 2) + wv, t + 1,
                           __ATOMIC_RELAXED, __HIP_MEMORY_SCOPE_AGENT);
    }
  }
}

// ---------------------------------------------------------------------------
// Kernel C: e[b] = h_T[b] . w_proj + b_proj   (h_T fp16 in hb0, T even)
// ---------------------------------------------------------------------------
__global__ __launch_bounds__(64) void proj_kernel(
    const _Float16* __restrict__ h, const float* __restrict__ w_proj,
    const float* __restrict__ b_proj, float* __restrict__ out)
{
  int b = blockIdx.x;
  int lane = threadIdx.x;
  float s = 0.f;
  #pragma unroll
  for (int i = 0; i < 8; ++i) {
    int j = lane + (i << 6);
    s += (float)h[((size_t)b << 9) + j] * w_proj[j];
  }
  #pragma unroll
  for (int off = 32; off > 0; off >>= 1) s += __shfl_down(s, off, 64);
  if (lane == 0) out[b] = s + b_proj[0];
}

// ---------------------------------------------------------------------------
extern "C" void kernel_launch(void* const* d_in, const int* in_sizes, int n_in,
                              void* d_out, int out_size, void* d_ws, size_t ws_size,
                              hipStream_t stream) {
  const float* x      = (const float*)d_in[0];
  const float* w_ih   = (const float*)d_in[1];
  const float* w_hh   = (const float*)d_in[2];
  const float* bias   = (const float*)d_in[3];
  const float* b_n    = (const float*)d_in[4];
  const float* w_proj = (const float*)d_in[5];
  const float* b_proj = (const float*)d_in[6];
  float* out = (float*)d_out;

  char* ws = (char*)d_ws;
  const size_t IG_BYTES = (size_t)T_ * B_ * G3_ * sizeof(_Float16); // 402,653,184
  const size_t HB_BYTES = (size_t)B_ * H_ * sizeof(_Float16);       // 262,144
  _Float16* igbuf = (_Float16*)ws;
  _Float16* hbuf0 = (_Float16*)(ws + IG_BYTES);
  _Float16* hbuf1 = (_Float16*)(ws + IG_BYTES + HB_BYTES);
  int*      flags = (int*)(ws + IG_BYTES + 2 * HB_BYTES);

  // zero h parity buffers (h(0)=0) + 512 wave-flags — capture-safe
  hipMemsetAsync(ws + IG_BYTES, 0, 2 * HB_BYTES + 4096, stream);

  dim3 gridA(G3_ / 64, (T_ * B_) / 64);   // (24, 2048)
  igates_gemm<<<gridA, 256, 0, stream>>>(x, w_ih, bias, igbuf);
  gru_scan<<<128, 256, 0, stream>>>(igbuf, w_hh, b_n, hbuf0, hbuf1, flags);
  proj_kernel<<<B_, 64, 0, stream>>>(hbuf0, w_proj, b_proj, out);
}